// Round 1
// baseline (1337.621 us; speedup 1.0000x reference)
//
#include <hip/hip_runtime.h>
#include <cmath>

#define NPROP 384
#define NB 2
#define NCLS 11
#define NFG 10
#define BC_TOTAL (NB*NFG)          // 20
#define M_TOTAL (NB*NPROP)         // 768
#define FLAT_PER_IMG (NFG*NPROP)   // 3840
#define DET 100

// ws layout (in floats / 4-byte words)
#define OFF_BOXES 0                // [BC][N][5]  38400
#define OFF_CORN  38400            // [BC][N][8]  61440  (x0..x3, y0..y3)
#define OFF_AREA  99840            // [BC][N]     7680
#define OFF_SCORE 107520           // [BC][N]     7680
#define OFF_VALID 115200           // [BC][N]     7680  (u32)
#define OFF_SUP   122880           // [BC][N][12] 92160 (u32 bitrows; 8B aligned)
#define OFF_KEEP  215040           // [BC][N]     7680  (u32)
// total 222720 words = 891 KB

__device__ float inter_area_dev(const float* ax, const float* ay,
                                const float* bx, const float* by) {
    float d1x[4], d1y[4], d2x[4], d2y[4];
#pragma unroll
    for (int k = 0; k < 4; ++k) {
        int k1 = (k + 1) & 3;
        d1x[k] = ax[k1] - ax[k]; d1y[k] = ay[k1] - ay[k];
        d2x[k] = bx[k1] - bx[k]; d2y[k] = by[k1] - by[k];
    }
    float ptx[24], pty[24];
    bool msk[24];
#pragma unroll
    for (int i = 0; i < 4; ++i) {
#pragma unroll
        for (int j = 0; j < 4; ++j) {
            float den = d1x[i]*d2y[j] - d1y[i]*d2x[j];
            float dfx = bx[j]-ax[i], dfy = by[j]-ay[i];
            float dens = (fabsf(den) < 1e-8f) ? 1.0f : den;
            float t = (dfx*d2y[j] - dfy*d2x[j]) / dens;
            float u = (dfx*d1y[i] - dfy*d1x[i]) / dens;
            bool ok = (fabsf(den) >= 1e-8f) && t >= 0.0f && t <= 1.0f
                                            && u >= 0.0f && u <= 1.0f;
            ptx[i*4+j] = ax[i] + t*d1x[i];
            pty[i*4+j] = ay[i] + t*d1y[i];
            msk[i*4+j] = ok;
        }
    }
#pragma unroll
    for (int i = 0; i < 4; ++i) {   // corners of A inside B
        bool allp = true, alln = true;
#pragma unroll
        for (int j = 0; j < 4; ++j) {
            float cr = d2x[j]*(ay[i]-by[j]) - d2y[j]*(ax[i]-bx[j]);
            allp = allp && (cr >= -1e-6f);
            alln = alln && (cr <= 1e-6f);
        }
        ptx[16+i] = ax[i]; pty[16+i] = ay[i]; msk[16+i] = allp || alln;
    }
#pragma unroll
    for (int i = 0; i < 4; ++i) {   // corners of B inside A
        bool allp = true, alln = true;
#pragma unroll
        for (int j = 0; j < 4; ++j) {
            float cr = d1x[j]*(by[i]-ay[j]) - d1y[j]*(bx[i]-ax[j]);
            allp = allp && (cr >= -1e-6f);
            alln = alln && (cr <= 1e-6f);
        }
        ptx[20+i] = bx[i]; pty[20+i] = by[i]; msk[20+i] = allp || alln;
    }
    int nv = 0; float sx = 0.f, sy = 0.f;
#pragma unroll
    for (int k = 0; k < 24; ++k)
        if (msk[k]) { nv++; sx += ptx[k]; sy += pty[k]; }
    float fm = (float)(nv > 1 ? nv : 1);
    float cx = sx / fm, cy = sy / fm;
    float ang[24];
#pragma unroll
    for (int k = 0; k < 24; ++k) {
        float qx = msk[k] ? ptx[k] : cx;
        float qy = msk[k] ? pty[k] : cy;
        ptx[k] = qx; pty[k] = qy;
        ang[k] = atan2f(qy - cy, qx - cx);   // parked pts: atan2(0,0)=0, like np
    }
    // stable insertion sort by (angle, original index) == jnp.argsort semantics
    int ord[24];
    for (int k = 0; k < 24; ++k) ord[k] = k;
    for (int i = 1; i < 24; ++i) {
        int oi = ord[i]; float ki = ang[oi];
        int j = i - 1;
        while (j >= 0 && ang[ord[j]] > ki) { ord[j+1] = ord[j]; --j; }
        ord[j+1] = oi;
    }
    float s = 0.f;
    for (int k = 0; k < 24; ++k) {
        int a = ord[k], b2 = ord[(k+1) == 24 ? 0 : (k+1)];
        s += ptx[a]*pty[b2] - pty[a]*ptx[b2];
    }
    float area = 0.5f * fabsf(s);
    return (nv >= 3) ? area : 0.0f;
}

__global__ __launch_bounds__(256)
void prep_kernel(const float* __restrict__ logits,
                 const float* __restrict__ boxreg,
                 const float* __restrict__ rrects,
                 float* __restrict__ ws) {
    int m = blockIdx.x * blockDim.x + threadIdx.x;
    if (m >= M_TOTAL) return;
    int b = m / NPROP, n = m % NPROP;
    float lg[NCLS];
    float mx = -INFINITY;
#pragma unroll
    for (int c = 0; c < NCLS; ++c) { lg[c] = logits[m*NCLS+c]; mx = fmaxf(mx, lg[c]); }
    float ex[NCLS]; float sum = 0.f;
#pragma unroll
    for (int c = 0; c < NCLS; ++c) { ex[c] = expf(lg[c]-mx); sum += ex[c]; }
    float axc = rrects[m*5+0], ayc = rrects[m*5+1];
    float aw  = rrects[m*5+2], ah  = rrects[m*5+3], aa = rrects[m*5+4];
    float* boxes = ws + OFF_BOXES;
    float* corn  = ws + OFF_CORN;
    float* areaA = ws + OFF_AREA;
    float* scoreA= ws + OFF_SCORE;
    unsigned int* validA = (unsigned int*)(ws + OFF_VALID);
    for (int cls = 1; cls < NCLS; ++cls) {
        int o = ((b*NFG + (cls-1))*NPROP + n);
        float prob = ex[cls] / sum;
        const float* rel = boxreg + m*(NCLS*5) + cls*5;
        float dx = rel[0] / 10.0f;
        float dy = rel[1] / 10.0f;
        float dw = fminf(rel[2] / 5.0f, 4.1351665567423205f);
        float dh = fminf(rel[3] / 5.0f, 4.1351665567423205f);
        float da = rel[4] / 1.0f;
        float px = dx*aw + axc;
        float py = dy*ah + ayc;
        float pw = expf(dw)*aw;
        float ph = expf(dh)*ah;
        float pa = da*57.29577951308232f + aa;
        float xm = pa + 180.0f;
        float r = fmodf(xm, 360.0f);
        if (r < 0.0f) r += 360.0f;
        pa = r - 180.0f;
        boxes[o*5+0]=px; boxes[o*5+1]=py; boxes[o*5+2]=pw; boxes[o*5+3]=ph; boxes[o*5+4]=pa;
        float t = pa * 0.017453292519943295f;
        float ct = cosf(t), st = sinf(t);
        float hx = pw*0.5f, hy = ph*0.5f;
        float lx[4] = {-hx, hx, hx, -hx};
        float ly[4] = {-hy, -hy, hy, hy};
#pragma unroll
        for (int k = 0; k < 4; ++k) {
            corn[o*8+k]   = px + lx[k]*ct - ly[k]*st;
            corn[o*8+4+k] = py + lx[k]*st + ly[k]*ct;
        }
        areaA[o]  = pw*ph;
        scoreA[o] = prob;
        validA[o] = (prob > 0.05f) ? 1u : 0u;
    }
}

__global__ __launch_bounds__(256)
void ioubits_kernel(float* __restrict__ ws) {
    const float* boxes = ws + OFF_BOXES;
    const float* corn  = ws + OFF_CORN;
    const float* areaA = ws + OFF_AREA;
    const unsigned int* validA = (const unsigned int*)(ws + OFF_VALID);
    unsigned long long* supb = (unsigned long long*)(ws + OFF_SUP);
    int wave = (blockIdx.x * blockDim.x + threadIdx.x) >> 6;
    int lane = threadIdx.x & 63;
    int jw = wave % 6;
    int i  = (wave / 6) % NPROP;
    int bc = wave / (6 * NPROP);
    if (bc >= BC_TOTAL) return;
    int rowi = bc*NPROP + i;
    int j = jw*64 + lane;
    int rowj = bc*NPROP + j;
    bool pred = false;
    if (validA[rowi] && validA[rowj]) {
        float cxi = boxes[rowi*5+0], cyi = boxes[rowi*5+1];
        float wi  = boxes[rowi*5+2], hi  = boxes[rowi*5+3];
        float cxj = boxes[rowj*5+0], cyj = boxes[rowj*5+1];
        float wj  = boxes[rowj*5+2], hj  = boxes[rowj*5+3];
        float ddx = cxi-cxj, ddy = cyi-cyj;
        float ri = 0.5f*sqrtf(wi*wi+hi*hi) + 0.5f*sqrtf(wj*wj+hj*hj);
        if (ddx*ddx + ddy*ddy <= ri*ri) {   // circles overlap: must compute
            float axp[4], ayp[4], bxp[4], byp[4];
#pragma unroll
            for (int k = 0; k < 4; ++k) {
                axp[k] = corn[rowi*8+k]; ayp[k] = corn[rowi*8+4+k];
                bxp[k] = corn[rowj*8+k]; byp[k] = corn[rowj*8+4+k];
            }
            float inter = inter_area_dev(axp, ayp, bxp, byp);
            float iou = inter / (areaA[rowi] + areaA[rowj] - inter + 1e-8f);
            pred = iou > 0.5f;
        }
    }
    unsigned long long bal = __ballot(pred);
    if (lane == 0) supb[rowi*6 + jw] = bal;
}

__global__ __launch_bounds__(384)
void nms_kernel(float* __restrict__ ws) {
    __shared__ float scoreL[NPROP];
    __shared__ unsigned int validL[NPROP];
    __shared__ int orderL[NPROP];
    int bc = blockIdx.x;
    const float* scoreA = ws + OFF_SCORE;
    const unsigned int* validA = (const unsigned int*)(ws + OFF_VALID);
    const unsigned int* supb = (const unsigned int*)(ws + OFF_SUP);
    unsigned int* keepA = (unsigned int*)(ws + OFF_KEEP);
    int t = threadIdx.x;
    if (t < NPROP) {
        scoreL[t] = scoreA[bc*NPROP+t];
        validL[t] = validA[bc*NPROP+t];
    }
    __syncthreads();
    if (t < NPROP) {
        float si = validL[t] ? scoreL[t] : -INFINITY;
        int r = 0;
        for (int k = 0; k < NPROP; ++k) {
            float sk = validL[k] ? scoreL[k] : -INFINITY;
            r += (sk > si) || (sk == si && k < t);
        }
        orderL[r] = t;
        keepA[bc*NPROP+t] = 0u;     // init (ws is poisoned)
    }
    __syncthreads();
    if (t == 0) {
        unsigned int sup[12];
#pragma unroll
        for (int w = 0; w < 12; ++w) sup[w] = 0u;
        for (int p = 0; p < NPROP; ++p) {
            int o = orderL[p];
            if (validL[o] && !((sup[o>>5] >> (o & 31)) & 1u)) {
                keepA[bc*NPROP+o] = 1u;
                const unsigned int* rb = supb + (bc*NPROP+o)*12;
#pragma unroll
                for (int w = 0; w < 12; ++w) sup[w] |= rb[w];
            }
        }
    }
}

__global__ __launch_bounds__(256)
void topk_kernel(const float* __restrict__ ws, float* __restrict__ out) {
    __shared__ int kcnt;
    __shared__ int   kidx[FLAT_PER_IMG];
    __shared__ float ksc [FLAT_PER_IMG];
    int b = blockIdx.x, t = threadIdx.x;
    const float* boxes  = ws + OFF_BOXES;
    const float* scoreA = ws + OFF_SCORE;
    const unsigned int* keepA = (const unsigned int*)(ws + OFF_KEEP);
    if (t == 0) kcnt = 0;
    for (int k = t; k < DET*6; k += 256) out[b*DET*6 + k] = 0.0f;
    for (int k = t; k < DET;   k += 256) out[NB*DET*6 + b*DET + k] = 0.0f;
    __syncthreads();
    for (int f = t; f < FLAT_PER_IMG; f += 256) {
        int idx = b*FLAT_PER_IMG + f;
        if (keepA[idx]) {
            int pos = atomicAdd(&kcnt, 1);
            kidx[pos] = f;
            ksc[pos]  = scoreA[idx];
        }
    }
    __syncthreads();
    int K = kcnt;
    for (int e = t; e < K; e += 256) {
        float s = ksc[e]; int f = kidx[e];
        int r = 0;
        for (int k = 0; k < K; ++k) {
            float sk = ksc[k]; int fk = kidx[k];
            r += (sk > s) || (sk == s && fk < f);
        }
        if (r < DET) {
            int src = b*FLAT_PER_IMG + f;
            float* row = out + (b*DET + r)*6;
#pragma unroll
            for (int q = 0; q < 5; ++q) row[q] = boxes[src*5+q];
            row[5] = s;
            out[NB*DET*6 + b*DET + r] = (float)(f / NPROP + 1);
        }
    }
}

extern "C" void kernel_launch(void* const* d_in, const int* in_sizes, int n_in,
                              void* d_out, int out_size, void* d_ws, size_t ws_size,
                              hipStream_t stream) {
    const float* logits = (const float*)d_in[0];
    const float* boxreg = (const float*)d_in[1];
    const float* rrects = (const float*)d_in[2];
    float* out = (float*)d_out;
    float* ws  = (float*)d_ws;
    (void)in_sizes; (void)n_in; (void)out_size; (void)ws_size;

    prep_kernel<<<(M_TOTAL + 255) / 256, 256, 0, stream>>>(logits, boxreg, rrects, ws);
    // waves = 20 * 384 * 6 = 46080; threads = 46080*64; blocks = 11520
    ioubits_kernel<<<(BC_TOTAL * NPROP * 6 * 64) / 256, 256, 0, stream>>>(ws);
    nms_kernel<<<BC_TOTAL, NPROP, 0, stream>>>(ws);
    topk_kernel<<<NB, 256, 0, stream>>>(ws, out);
}

// Round 2
// 707.419 us; speedup vs baseline: 1.8908x; 1.8908x over previous
//
#include <hip/hip_runtime.h>
#include <cmath>

#define NPROP 384
#define NB 2
#define NCLS 11
#define NFG 10
#define BC_TOTAL (NB*NFG)          // 20
#define M_TOTAL (NB*NPROP)         // 768
#define FLAT_PER_IMG (NFG*NPROP)   // 3840
#define DET 100

// ws layout (in floats / 4-byte words)
#define OFF_BOXES 0                // [BC][N][5]  38400
#define OFF_CORN  38400            // [BC][N][8]  61440  (x0..x3, y0..y3)
#define OFF_AREA  99840            // [BC][N]     7680
#define OFF_SCORE 107520           // [BC][N]     7680
#define OFF_VALID 115200           // [BC][N]     7680  (u32)
#define OFF_SUP   122880           // [BC][N][12] 92160 (u32 bitrows; 8B aligned)
#define OFF_MS    215040           // [B][FLAT]   7680  masked scores (keep? s : -1)
// total 222720 words = 891 KB

__device__ float inter_area_dev(const float* ax, const float* ay,
                                const float* bx, const float* by) {
    float d1x[4], d1y[4], d2x[4], d2y[4];
#pragma unroll
    for (int k = 0; k < 4; ++k) {
        int k1 = (k + 1) & 3;
        d1x[k] = ax[k1] - ax[k]; d1y[k] = ay[k1] - ay[k];
        d2x[k] = bx[k1] - bx[k]; d2y[k] = by[k1] - by[k];
    }
    float ptx[24], pty[24];
    bool msk[24];
#pragma unroll
    for (int i = 0; i < 4; ++i) {
#pragma unroll
        for (int j = 0; j < 4; ++j) {
            float den = d1x[i]*d2y[j] - d1y[i]*d2x[j];
            float dfx = bx[j]-ax[i], dfy = by[j]-ay[i];
            float dens = (fabsf(den) < 1e-8f) ? 1.0f : den;
            float t = (dfx*d2y[j] - dfy*d2x[j]) / dens;
            float u = (dfx*d1y[i] - dfy*d1x[i]) / dens;
            bool ok = (fabsf(den) >= 1e-8f) && t >= 0.0f && t <= 1.0f
                                            && u >= 0.0f && u <= 1.0f;
            ptx[i*4+j] = ax[i] + t*d1x[i];
            pty[i*4+j] = ay[i] + t*d1y[i];
            msk[i*4+j] = ok;
        }
    }
#pragma unroll
    for (int i = 0; i < 4; ++i) {   // corners of A inside B
        bool allp = true, alln = true;
#pragma unroll
        for (int j = 0; j < 4; ++j) {
            float cr = d2x[j]*(ay[i]-by[j]) - d2y[j]*(ax[i]-bx[j]);
            allp = allp && (cr >= -1e-6f);
            alln = alln && (cr <= 1e-6f);
        }
        ptx[16+i] = ax[i]; pty[16+i] = ay[i]; msk[16+i] = allp || alln;
    }
#pragma unroll
    for (int i = 0; i < 4; ++i) {   // corners of B inside A
        bool allp = true, alln = true;
#pragma unroll
        for (int j = 0; j < 4; ++j) {
            float cr = d1x[j]*(by[i]-ay[j]) - d1y[j]*(bx[i]-ax[j]);
            allp = allp && (cr >= -1e-6f);
            alln = alln && (cr <= 1e-6f);
        }
        ptx[20+i] = bx[i]; pty[20+i] = by[i]; msk[20+i] = allp || alln;
    }
    int nv = 0; float sx = 0.f, sy = 0.f;
#pragma unroll
    for (int k = 0; k < 24; ++k)
        if (msk[k]) { nv++; sx += ptx[k]; sy += pty[k]; }
    float fm = (float)(nv > 1 ? nv : 1);
    float cx = sx / fm, cy = sy / fm;
    float ang[24];
#pragma unroll
    for (int k = 0; k < 24; ++k) {
        float qx = msk[k] ? ptx[k] : cx;
        float qy = msk[k] ? pty[k] : cy;
        ptx[k] = qx; pty[k] = qy;
        ang[k] = atan2f(qy - cy, qx - cx);   // parked pts: atan2(0,0)=0, like np
    }
    // stable insertion sort by (angle, original index) == jnp.argsort semantics
    int ord[24];
    for (int k = 0; k < 24; ++k) ord[k] = k;
    for (int i = 1; i < 24; ++i) {
        int oi = ord[i]; float ki = ang[oi];
        int j = i - 1;
        while (j >= 0 && ang[ord[j]] > ki) { ord[j+1] = ord[j]; --j; }
        ord[j+1] = oi;
    }
    float s = 0.f;
    for (int k = 0; k < 24; ++k) {
        int a = ord[k], b2 = ord[(k+1) == 24 ? 0 : (k+1)];
        s += ptx[a]*pty[b2] - pty[a]*ptx[b2];
    }
    float area = 0.5f * fabsf(s);
    return (nv >= 3) ? area : 0.0f;
}

__global__ __launch_bounds__(256)
void prep_kernel(const float* __restrict__ logits,
                 const float* __restrict__ boxreg,
                 const float* __restrict__ rrects,
                 float* __restrict__ ws,
                 float* __restrict__ out) {
    int m = blockIdx.x * blockDim.x + threadIdx.x;
    if (m >= M_TOTAL) return;
    // zero-init output (1400 floats total; d_out is poisoned pre-launch)
    out[m] = 0.0f;
    if (m + M_TOTAL < NB*DET*6 + NB*DET) out[m + M_TOTAL] = 0.0f;
    int b = m / NPROP, n = m % NPROP;
    float lg[NCLS];
    float mx = -INFINITY;
#pragma unroll
    for (int c = 0; c < NCLS; ++c) { lg[c] = logits[m*NCLS+c]; mx = fmaxf(mx, lg[c]); }
    float ex[NCLS]; float sum = 0.f;
#pragma unroll
    for (int c = 0; c < NCLS; ++c) { ex[c] = expf(lg[c]-mx); sum += ex[c]; }
    float axc = rrects[m*5+0], ayc = rrects[m*5+1];
    float aw  = rrects[m*5+2], ah  = rrects[m*5+3], aa = rrects[m*5+4];
    float* boxes = ws + OFF_BOXES;
    float* corn  = ws + OFF_CORN;
    float* areaA = ws + OFF_AREA;
    float* scoreA= ws + OFF_SCORE;
    unsigned int* validA = (unsigned int*)(ws + OFF_VALID);
    for (int cls = 1; cls < NCLS; ++cls) {
        int o = ((b*NFG + (cls-1))*NPROP + n);
        float prob = ex[cls] / sum;
        const float* rel = boxreg + m*(NCLS*5) + cls*5;
        float dx = rel[0] / 10.0f;
        float dy = rel[1] / 10.0f;
        float dw = fminf(rel[2] / 5.0f, 4.1351665567423205f);
        float dh = fminf(rel[3] / 5.0f, 4.1351665567423205f);
        float da = rel[4] / 1.0f;
        float px = dx*aw + axc;
        float py = dy*ah + ayc;
        float pw = expf(dw)*aw;
        float ph = expf(dh)*ah;
        float pa = da*57.29577951308232f + aa;
        float xm = pa + 180.0f;
        float r = fmodf(xm, 360.0f);
        if (r < 0.0f) r += 360.0f;
        pa = r - 180.0f;
        boxes[o*5+0]=px; boxes[o*5+1]=py; boxes[o*5+2]=pw; boxes[o*5+3]=ph; boxes[o*5+4]=pa;
        float t = pa * 0.017453292519943295f;
        float ct = cosf(t), st = sinf(t);
        float hx = pw*0.5f, hy = ph*0.5f;
        float lx[4] = {-hx, hx, hx, -hx};
        float ly[4] = {-hy, -hy, hy, hy};
#pragma unroll
        for (int k = 0; k < 4; ++k) {
            corn[o*8+k]   = px + lx[k]*ct - ly[k]*st;
            corn[o*8+4+k] = py + lx[k]*st + ly[k]*ct;
        }
        areaA[o]  = pw*ph;
        scoreA[o] = prob;
        validA[o] = (prob > 0.05f) ? 1u : 0u;
    }
}

__global__ __launch_bounds__(256)
void ioubits_kernel(float* __restrict__ ws) {
    const float* boxes = ws + OFF_BOXES;
    const float* corn  = ws + OFF_CORN;
    const float* areaA = ws + OFF_AREA;
    const unsigned int* validA = (const unsigned int*)(ws + OFF_VALID);
    unsigned long long* supb = (unsigned long long*)(ws + OFF_SUP);
    int wave = (blockIdx.x * blockDim.x + threadIdx.x) >> 6;
    int lane = threadIdx.x & 63;
    int jw = wave % 6;
    int i  = (wave / 6) % NPROP;
    int bc = wave / (6 * NPROP);
    if (bc >= BC_TOTAL) return;
    int rowi = bc*NPROP + i;
    int j = jw*64 + lane;
    int rowj = bc*NPROP + j;
    bool pred = false;
    if (validA[rowi] && validA[rowj]) {
        float cxi = boxes[rowi*5+0], cyi = boxes[rowi*5+1];
        float wi  = boxes[rowi*5+2], hi  = boxes[rowi*5+3];
        float cxj = boxes[rowj*5+0], cyj = boxes[rowj*5+1];
        float wj  = boxes[rowj*5+2], hj  = boxes[rowj*5+3];
        float ddx = cxi-cxj, ddy = cyi-cyj;
        float ri = 0.5f*sqrtf(wi*wi+hi*hi) + 0.5f*sqrtf(wj*wj+hj*hj);
        if (ddx*ddx + ddy*ddy <= ri*ri) {   // circles overlap: must compute
            float axp[4], ayp[4], bxp[4], byp[4];
#pragma unroll
            for (int k = 0; k < 4; ++k) {
                axp[k] = corn[rowi*8+k]; ayp[k] = corn[rowi*8+4+k];
                bxp[k] = corn[rowj*8+k]; byp[k] = corn[rowj*8+4+k];
            }
            float inter = inter_area_dev(axp, ayp, bxp, byp);
            float iou = inter / (areaA[rowi] + areaA[rowj] - inter + 1e-8f);
            pred = iou > 0.5f;
        }
    }
    unsigned long long bal = __ballot(pred);
    if (lane == 0) supb[rowi*6 + jw] = bal;
}

__global__ __launch_bounds__(384)
void nms_kernel(float* __restrict__ ws) {
    __shared__ float scoreL[NPROP];
    __shared__ unsigned int validL[NPROP];
    __shared__ int orderL[NPROP];
    __shared__ unsigned int supL[NPROP*12];   // 18.4 KB
    __shared__ unsigned char keepS[NPROP];
    __shared__ int nvalidS;
    int bc = blockIdx.x;
    const float* scoreA = ws + OFF_SCORE;
    const unsigned int* validA = (const unsigned int*)(ws + OFF_VALID);
    const unsigned int* supbG = (const unsigned int*)(ws + OFF_SUP);
    float* msA = ws + OFF_MS;
    int t = threadIdx.x;
    if (t == 0) nvalidS = 0;
    scoreL[t] = scoreA[bc*NPROP+t];
    validL[t] = validA[bc*NPROP+t];
    keepS[t] = 0;
    __syncthreads();
    {
        float si = validL[t] ? scoreL[t] : -INFINITY;
        int r = 0;
        for (int k = 0; k < NPROP; ++k) {
            float sk = validL[k] ? scoreL[k] : -INFINITY;
            r += (sk > si) || (sk == si && k < t);
        }
        orderL[r] = t;
        if (validL[t]) atomicAdd(&nvalidS, 1);
    }
    // preload all suppress-bit rows into LDS (parallel, coalesced)
    for (int k = t; k < NPROP*12; k += NPROP) supL[k] = supbG[bc*NPROP*12 + k];
    __syncthreads();
    if (t == 0) {
        unsigned int sup[12];
#pragma unroll
        for (int w = 0; w < 12; ++w) sup[w] = 0u;
        int NV = nvalidS;
        for (int p = 0; p < NV; ++p) {      // valid entries sort first
            int o = orderL[p];
            if (!((sup[o>>5] >> (o & 31)) & 1u)) {
                keepS[o] = 1;
#pragma unroll
                for (int w = 0; w < 12; ++w) sup[w] |= supL[o*12 + w];
            }
        }
    }
    __syncthreads();
    // masked scores for topk: kept -> score, else -1 (matches reference where())
    msA[bc*NPROP + t] = keepS[t] ? scoreL[t] : -1.0f;
}

// one thread per flat candidate; rank among all via broadcast float4 reads
__global__ __launch_bounds__(256)
void topk_kernel(const float* __restrict__ ws, float* __restrict__ out) {
    int b = blockIdx.x / (FLAT_PER_IMG/256);        // image
    int f = (blockIdx.x % (FLAT_PER_IMG/256)) * 256 + threadIdx.x;
    const float* ms = ws + OFF_MS + b*FLAT_PER_IMG;
    const float* boxes = ws + OFF_BOXES;
    float s = ms[f];
    const float4* ms4 = (const float4*)ms;
    int r = 0;
#pragma unroll 8
    for (int k4 = 0; k4 < FLAT_PER_IMG/4; ++k4) {
        float4 v = ms4[k4];
        int k = k4*4;
        r += (v.x > s) || (v.x == s && (k+0) < f);
        r += (v.y > s) || (v.y == s && (k+1) < f);
        r += (v.z > s) || (v.z == s && (k+2) < f);
        r += (v.w > s) || (v.w == s && (k+3) < f);
    }
    if (s > 0.0f && r < DET) {
        int src = b*FLAT_PER_IMG + f;
        float* row = out + (b*DET + r)*6;
#pragma unroll
        for (int q = 0; q < 5; ++q) row[q] = boxes[src*5+q];
        row[5] = s;
        out[NB*DET*6 + b*DET + r] = (float)(f / NPROP + 1);
    }
}

extern "C" void kernel_launch(void* const* d_in, const int* in_sizes, int n_in,
                              void* d_out, int out_size, void* d_ws, size_t ws_size,
                              hipStream_t stream) {
    const float* logits = (const float*)d_in[0];
    const float* boxreg = (const float*)d_in[1];
    const float* rrects = (const float*)d_in[2];
    float* out = (float*)d_out;
    float* ws  = (float*)d_ws;
    (void)in_sizes; (void)n_in; (void)out_size; (void)ws_size;

    prep_kernel<<<(M_TOTAL + 255) / 256, 256, 0, stream>>>(logits, boxreg, rrects, ws, out);
    // waves = 20 * 384 * 6 = 46080; blocks = 11520
    ioubits_kernel<<<(BC_TOTAL * NPROP * 6 * 64) / 256, 256, 0, stream>>>(ws);
    nms_kernel<<<BC_TOTAL, NPROP, 0, stream>>>(ws);
    topk_kernel<<<NB * (FLAT_PER_IMG/256), 256, 0, stream>>>(ws, out);
}

// Round 3
// 332.746 us; speedup vs baseline: 4.0199x; 2.1260x over previous
//
#include <hip/hip_runtime.h>
#include <cmath>

#define NPROP 384
#define NB 2
#define NCLS 11
#define NFG 10
#define BC_TOTAL (NB*NFG)          // 20
#define M_TOTAL (NB*NPROP)         // 768
#define FLAT_PER_IMG (NFG*NPROP)   // 3840
#define DET 100

// ws layout (in 4-byte words) — total 222752 words = 891 KB (proven footprint)
#define OFF_BOXES 0                // [BC][N][5]  38400
#define OFF_CORN  38400            // [BC][N][8]  61440  (x0..x3, y0..y3)
#define OFF_AREA  99840            // [BC][N]     7680
#define OFF_SCORE 107520           // [BC][N]     7680
#define OFF_VIDX  115200           // [BC][N]     7680 (u32 compacted valid indices)
#define OFF_SUP   122880           // [BC][N][12] 92160 (u32 suppress bitrows)
#define OFF_MS    215040           // [B][FLAT]   7680  masked scores (keep? s : -1)
#define OFF_VCNT  222720           // [BC]        32   (u32 counts)

// Register-only intersection area, faithful to the reference's quirky
// park-at-centroid + sort-all-24 + shoelace semantics. Sorting is a
// bitonic-32 network (static indexing -> SROA keeps everything in VGPRs).
// Sort key: diamond pseudo-angle (monotone w.r.t. atan2 order) mapped to an
// order-preserving uint with the candidate index in the low 5 bits (stable
// tie-break, identical to jnp.argsort for exact angle ties).
__device__ float inter_area_net(const float ax[4], const float ay[4],
                                const float bx[4], const float by[4]) {
    float d1x[4], d1y[4], d2x[4], d2y[4];
#pragma unroll
    for (int k = 0; k < 4; ++k) {
        int k1 = (k + 1) & 3;
        d1x[k] = ax[k1] - ax[k]; d1y[k] = ay[k1] - ay[k];
        d2x[k] = bx[k1] - bx[k]; d2y[k] = by[k1] - by[k];
    }
    float ex[32], ey[32];
    bool msk[24];
#pragma unroll
    for (int i = 0; i < 4; ++i) {
#pragma unroll
        for (int j = 0; j < 4; ++j) {
            float den = d1x[i]*d2y[j] - d1y[i]*d2x[j];
            float dfx = bx[j]-ax[i], dfy = by[j]-ay[i];
            float dens = (fabsf(den) < 1e-8f) ? 1.0f : den;
            float t = (dfx*d2y[j] - dfy*d2x[j]) / dens;
            float u = (dfx*d1y[i] - dfy*d1x[i]) / dens;
            bool ok = (fabsf(den) >= 1e-8f) && t >= 0.0f && t <= 1.0f
                                            && u >= 0.0f && u <= 1.0f;
            ex[i*4+j] = ax[i] + t*d1x[i];
            ey[i*4+j] = ay[i] + t*d1y[i];
            msk[i*4+j] = ok;
        }
    }
#pragma unroll
    for (int i = 0; i < 4; ++i) {   // corners of A inside B
        bool allp = true, alln = true;
#pragma unroll
        for (int j = 0; j < 4; ++j) {
            float cr = d2x[j]*(ay[i]-by[j]) - d2y[j]*(ax[i]-bx[j]);
            allp = allp && (cr >= -1e-6f);
            alln = alln && (cr <= 1e-6f);
        }
        ex[16+i] = ax[i]; ey[16+i] = ay[i]; msk[16+i] = allp || alln;
    }
#pragma unroll
    for (int i = 0; i < 4; ++i) {   // corners of B inside A
        bool allp = true, alln = true;
#pragma unroll
        for (int j = 0; j < 4; ++j) {
            float cr = d1x[j]*(by[i]-ay[j]) - d1y[j]*(bx[i]-ax[j]);
            allp = allp && (cr >= -1e-6f);
            alln = alln && (cr <= 1e-6f);
        }
        ex[20+i] = bx[i]; ey[20+i] = by[i]; msk[20+i] = allp || alln;
    }
    int nv = 0; float sx = 0.f, sy = 0.f;
#pragma unroll
    for (int k = 0; k < 24; ++k)
        if (msk[k]) { nv++; sx += ex[k]; sy += ey[k]; }
    float fm = (float)(nv > 1 ? nv : 1);
    float cx = sx / fm, cy = sy / fm;
    unsigned key[32];
#pragma unroll
    for (int k = 0; k < 24; ++k) {
        float qx = msk[k] ? ex[k] : cx;
        float qy = msk[k] ? ey[k] : cy;
        ex[k] = qx; ey[k] = qy;
        float dx = qx - cx, dy = qy - cy;        // parked: dx=dy=+0
        float den = fabsf(dx) + fabsf(dy);
        float r = (den > 0.0f) ? dy / den : 0.0f;
        float p = (dx >= 0.0f) ? r : ((dy >= 0.0f) ? 2.0f - r : -2.0f - r);
        p = p + 0.0f;                             // canonicalize -0 -> +0
        unsigned u = __float_as_uint(p);
        u = (u & 0x80000000u) ? ~u : (u | 0x80000000u);
        key[k] = (u & 0xFFFFFFE0u) | (unsigned)k;
    }
#pragma unroll
    for (int k = 24; k < 32; ++k) { key[k] = 0xFFFFFFFFu; ex[k] = 0.f; ey[k] = 0.f; }
    // bitonic sort, 32 elements ascending, fully unrolled (240 CEs)
#pragma unroll
    for (int k = 2; k <= 32; k <<= 1) {
#pragma unroll
        for (int j = k >> 1; j > 0; j >>= 1) {
#pragma unroll
            for (int i = 0; i < 32; ++i) {
                int l = i ^ j;
                if (l > i) {
                    bool up = ((i & k) == 0);
                    unsigned ka = key[i], kb = key[l];
                    bool sw = up ? (ka > kb) : (ka < kb);
                    float xa = ex[i], xb = ex[l];
                    float ya = ey[i], yb = ey[l];
                    key[i] = sw ? kb : ka; key[l] = sw ? ka : kb;
                    ex[i]  = sw ? xb : xa; ex[l]  = sw ? xa : xb;
                    ey[i]  = sw ? yb : ya; ey[l]  = sw ? ya : yb;
                }
            }
        }
    }
    float s = 0.f;
#pragma unroll
    for (int k = 0; k < 24; ++k) {
        int n = (k + 1 == 24) ? 0 : (k + 1);
        s += ex[k]*ey[n] - ey[k]*ex[n];
    }
    float area = 0.5f * fabsf(s);
    return (nv >= 3) ? area : 0.0f;
}

__global__ __launch_bounds__(256)
void prep_kernel(const float* __restrict__ logits,
                 const float* __restrict__ boxreg,
                 const float* __restrict__ rrects,
                 float* __restrict__ ws,
                 float* __restrict__ out) {
    int m = blockIdx.x * blockDim.x + threadIdx.x;
    if (m >= M_TOTAL) return;
    out[m] = 0.0f;                               // zero 1400-float output
    if (m + M_TOTAL < NB*DET*6 + NB*DET) out[m + M_TOTAL] = 0.0f;
    int b = m / NPROP, n = m % NPROP;
    float lg[NCLS];
    float mx = -INFINITY;
#pragma unroll
    for (int c = 0; c < NCLS; ++c) { lg[c] = logits[m*NCLS+c]; mx = fmaxf(mx, lg[c]); }
    float exo[NCLS]; float sum = 0.f;
#pragma unroll
    for (int c = 0; c < NCLS; ++c) { exo[c] = expf(lg[c]-mx); sum += exo[c]; }
    float axc = rrects[m*5+0], ayc = rrects[m*5+1];
    float aw  = rrects[m*5+2], ah  = rrects[m*5+3], aa = rrects[m*5+4];
    float* boxes = ws + OFF_BOXES;
    float* corn  = ws + OFF_CORN;
    float* areaA = ws + OFF_AREA;
    float* scoreA= ws + OFF_SCORE;
    for (int cls = 1; cls < NCLS; ++cls) {
        int o = ((b*NFG + (cls-1))*NPROP + n);
        float prob = exo[cls] / sum;
        const float* rel = boxreg + m*(NCLS*5) + cls*5;
        float dx = rel[0] / 10.0f;
        float dy = rel[1] / 10.0f;
        float dw = fminf(rel[2] / 5.0f, 4.1351665567423205f);
        float dh = fminf(rel[3] / 5.0f, 4.1351665567423205f);
        float da = rel[4];
        float px = dx*aw + axc;
        float py = dy*ah + ayc;
        float pw = expf(dw)*aw;
        float ph = expf(dh)*ah;
        float pa = da*57.29577951308232f + aa;
        float xm = pa + 180.0f;
        float r = fmodf(xm, 360.0f);
        if (r < 0.0f) r += 360.0f;
        pa = r - 180.0f;
        boxes[o*5+0]=px; boxes[o*5+1]=py; boxes[o*5+2]=pw; boxes[o*5+3]=ph; boxes[o*5+4]=pa;
        float t = pa * 0.017453292519943295f;
        float ct = cosf(t), st = sinf(t);
        float hx = pw*0.5f, hy = ph*0.5f;
        float lx[4] = {-hx, hx, hx, -hx};
        float ly[4] = {-hy, -hy, hy, hy};
#pragma unroll
        for (int k = 0; k < 4; ++k) {
            corn[o*8+k]   = px + lx[k]*ct - ly[k]*st;
            corn[o*8+4+k] = py + lx[k]*st + ly[k]*ct;
        }
        areaA[o]  = pw*ph;
        scoreA[o] = prob;
    }
}

// zero suppress bitrows + compact valid indices per (b,cls)
__global__ __launch_bounds__(384)
void compact_kernel(float* __restrict__ ws) {
    __shared__ int cntS;
    int bc = blockIdx.x, t = threadIdx.x;
    unsigned int* supw = (unsigned int*)(ws + OFF_SUP);
    unsigned int* vidx = (unsigned int*)(ws + OFF_VIDX);
    unsigned int* vcnt = (unsigned int*)(ws + OFF_VCNT);
    int r0 = (bc*NPROP + t)*12;
#pragma unroll
    for (int w = 0; w < 12; ++w) supw[r0 + w] = 0u;
    if (t == 0) cntS = 0;
    __syncthreads();
    float sc = ws[OFF_SCORE + bc*NPROP + t];
    if (sc > 0.05f) {
        int p = atomicAdd(&cntS, 1);
        vidx[bc*NPROP + p] = (unsigned)t;
    }
    __syncthreads();
    if (t == 0) vcnt[bc] = (unsigned)cntS;
}

// one wave per (bc, a, 64-chunk of b) over COMPACTED valid indices
__global__ __launch_bounds__(256)
void heavy_kernel(float* __restrict__ ws) {
    const float* boxes = ws + OFF_BOXES;
    const float* corn  = ws + OFF_CORN;
    const float* areaA = ws + OFF_AREA;
    const unsigned int* vidx = (const unsigned int*)(ws + OFF_VIDX);
    const unsigned int* vcnt = (const unsigned int*)(ws + OFF_VCNT);
    unsigned int* supw = (unsigned int*)(ws + OFF_SUP);
    int wave = (blockIdx.x * blockDim.x + threadIdx.x) >> 6;
    int lane = threadIdx.x & 63;
    int bw = wave % 6;
    int a  = (wave / 6) % NPROP;
    int bc = wave / (6 * NPROP);
    if (bc >= BC_TOTAL) return;
    int cnt = (int)vcnt[bc];
    if (a >= cnt || bw*64 >= cnt) return;        // wave-uniform exits
    int i = (int)vidx[bc*NPROP + a];
    int rowi = bc*NPROP + i;
    int b = bw*64 + lane;
    bool act = b < cnt;
    int j = act ? (int)vidx[bc*NPROP + b] : i;
    int rowj = bc*NPROP + j;
    bool go = act && (j != i);
    if (go) {
        float cxi = boxes[rowi*5+0], cyi = boxes[rowi*5+1];
        float wi  = boxes[rowi*5+2], hi  = boxes[rowi*5+3];
        float cxj = boxes[rowj*5+0], cyj = boxes[rowj*5+1];
        float wj  = boxes[rowj*5+2], hj  = boxes[rowj*5+3];
        float ddx = cxi-cxj, ddy = cyi-cyj;
        float rr = 0.5f*sqrtf(wi*wi+hi*hi) + 0.5f*sqrtf(wj*wj+hj*hj);
        go = (ddx*ddx + ddy*ddy <= rr*rr);
        if (go) {
            float A = areaA[rowi], Bv = areaA[rowj];
            float mn = fminf(A, Bv);
            go = (3.0f*mn > A + Bv);             // else iou <= 0.5 provably
        }
    }
    bool pred = false;
    if (go) {
        float axp[4], ayp[4], bxp[4], byp[4];
#pragma unroll
        for (int k = 0; k < 4; ++k) {
            axp[k] = corn[rowi*8+k]; ayp[k] = corn[rowi*8+4+k];
            bxp[k] = corn[rowj*8+k]; byp[k] = corn[rowj*8+4+k];
        }
        float inter = inter_area_net(axp, ayp, bxp, byp);
        float iou = inter / (areaA[rowi] + areaA[rowj] - inter + 1e-8f);
        pred = iou > 0.5f;
    }
    if (pred) atomicOr(&supw[rowi*12 + (j >> 5)], 1u << (j & 31));
}

__global__ __launch_bounds__(384)
void nms_kernel(float* __restrict__ ws) {
    __shared__ float scoreL[NPROP];
    __shared__ int orderL[NPROP];
    __shared__ unsigned int supL[NPROP*12];   // 18.4 KB
    __shared__ unsigned char keepS[NPROP];
    __shared__ int nvalidS;
    int bc = blockIdx.x;
    const float* scoreA = ws + OFF_SCORE;
    const unsigned int* supbG = (const unsigned int*)(ws + OFF_SUP);
    float* msA = ws + OFF_MS;
    int t = threadIdx.x;
    if (t == 0) nvalidS = 0;
    scoreL[t] = scoreA[bc*NPROP+t];
    keepS[t] = 0;
    __syncthreads();
    {
        bool vi = scoreL[t] > 0.05f;
        float si = vi ? scoreL[t] : -INFINITY;
        int r = 0;
        for (int k = 0; k < NPROP; ++k) {
            bool vk = scoreL[k] > 0.05f;
            float sk = vk ? scoreL[k] : -INFINITY;
            r += (sk > si) || (sk == si && k < t);
        }
        orderL[r] = t;
        if (vi) atomicAdd(&nvalidS, 1);
    }
    for (int k = t; k < NPROP*12; k += NPROP) supL[k] = supbG[bc*NPROP*12 + k];
    __syncthreads();
    if (t == 0) {
        unsigned int sup[12];
#pragma unroll
        for (int w = 0; w < 12; ++w) sup[w] = 0u;
        int NV = nvalidS;
        for (int p = 0; p < NV; ++p) {      // valid entries sort first
            int o = orderL[p];
            if (!((sup[o>>5] >> (o & 31)) & 1u)) {
                keepS[o] = 1;
#pragma unroll
                for (int w = 0; w < 12; ++w) sup[w] |= supL[o*12 + w];
            }
        }
    }
    __syncthreads();
    msA[bc*NPROP + t] = keepS[t] ? scoreL[t] : -1.0f;
}

// one thread per flat candidate; rank among all via broadcast float4 reads
__global__ __launch_bounds__(256)
void topk_kernel(const float* __restrict__ ws, float* __restrict__ out) {
    int b = blockIdx.x / (FLAT_PER_IMG/256);        // image
    int f = (blockIdx.x % (FLAT_PER_IMG/256)) * 256 + threadIdx.x;
    const float* ms = ws + OFF_MS + b*FLAT_PER_IMG;
    const float* boxes = ws + OFF_BOXES;
    float s = ms[f];
    const float4* ms4 = (const float4*)ms;
    int r = 0;
#pragma unroll 8
    for (int k4 = 0; k4 < FLAT_PER_IMG/4; ++k4) {
        float4 v = ms4[k4];
        int k = k4*4;
        r += (v.x > s) || (v.x == s && (k+0) < f);
        r += (v.y > s) || (v.y == s && (k+1) < f);
        r += (v.z > s) || (v.z == s && (k+2) < f);
        r += (v.w > s) || (v.w == s && (k+3) < f);
    }
    if (s > 0.0f && r < DET) {
        int src = b*FLAT_PER_IMG + f;
        float* row = out + (b*DET + r)*6;
#pragma unroll
        for (int q = 0; q < 5; ++q) row[q] = boxes[src*5+q];
        row[5] = s;
        out[NB*DET*6 + b*DET + r] = (float)(f / NPROP + 1);
    }
}

extern "C" void kernel_launch(void* const* d_in, const int* in_sizes, int n_in,
                              void* d_out, int out_size, void* d_ws, size_t ws_size,
                              hipStream_t stream) {
    const float* logits = (const float*)d_in[0];
    const float* boxreg = (const float*)d_in[1];
    const float* rrects = (const float*)d_in[2];
    float* out = (float*)d_out;
    float* ws  = (float*)d_ws;
    (void)in_sizes; (void)n_in; (void)out_size; (void)ws_size;

    prep_kernel<<<(M_TOTAL + 255) / 256, 256, 0, stream>>>(logits, boxreg, rrects, ws, out);
    compact_kernel<<<BC_TOTAL, NPROP, 0, stream>>>(ws);
    // 20*384*6 = 46080 waves -> 11520 blocks of 4 waves; most exit immediately
    heavy_kernel<<<(BC_TOTAL * NPROP * 6 * 64) / 256, 256, 0, stream>>>(ws);
    nms_kernel<<<BC_TOTAL, NPROP, 0, stream>>>(ws);
    topk_kernel<<<NB * (FLAT_PER_IMG/256), 256, 0, stream>>>(ws, out);
}